// Round 10
// baseline (557.314 us; speedup 1.0000x reference)
//
#include <hip/hip_runtime.h>
#include <hip/hip_bf16.h>
#include <math.h>

#define T_LEN 4096
#define D_DIM 512
#define F_DIM 8192
#define NCHUNK 64
#define CLEN 64

typedef short short8 __attribute__((ext_vector_type(8)));
typedef float f32x4 __attribute__((ext_vector_type(4)));
typedef unsigned short u16;
typedef unsigned int u32;

// ---------------- helpers ----------------
__device__ inline float wave_sum(float v) {
#pragma unroll
  for (int o = 32; o; o >>= 1) v += __shfl_xor(v, o);
  return v;
}

__device__ inline u16 f2bf_bits(float v) {
  __hip_bfloat16 h = __float2bfloat16(v);
  return *(u16*)&h;
}

__device__ inline void gl_lds16(const void* g, void* l) {
  __builtin_amdgcn_global_load_lds((const __attribute__((address_space(1))) void*)g,
                                   (__attribute__((address_space(3))) void*)l, 16, 0, 0);
}

// start[] may arrive as 1-byte bools or int32 {0,1}.
__global__ void detect_start(const unsigned char* __restrict__ s8, int* __restrict__ mode) {
  __shared__ int found;
  if (threadIdx.x == 0) found = 0;
  __syncthreads();
  for (int i = threadIdx.x; i < 4096; i += 256)
    if ((i & 3) && s8[i]) found = 1;  // benign race, same value
  __syncthreads();
  if (threadIdx.x == 0) mode[0] = found;  // 1 = byte layout, 0 = int32 layout
}

__device__ inline int read_start(const unsigned char* s8, const int* s32, int mode, int t) {
  return mode ? (int)s8[t] : s32[t];
}

// ---------------- fp32 -> bf16(bits) convert (plain) ----------------
__global__ void f2bf(const float* __restrict__ s, u16* __restrict__ d, int n) {
  int i = blockIdx.x * 256 + threadIdx.x;
  if (i < n) d[i] = f2bf_bits(s[i]);
}

// W1 convert with per-row granule swizzle: dst[d][e ^ ((d&7)<<3)] = W1[d][e]
__global__ void k_w1conv(const float* __restrict__ src, u16* __restrict__ dst, int n) {
  int i = blockIdx.x * 256 + threadIdx.x;
  if (i >= n) return;
  int d = (i >> 9) & 511;
  int e = i & 511;
  dst[(i & ~511) | (e ^ ((d & 7) << 3))] = f2bf_bits(src[i]);
}

// fused per-layer weight conversion:
//   wcat = concat [Wtr_l; Wc_l] (128 x 512), unswizzled (BK=32 gemm)
//   w0bf: K-permute (f = r*128+2c+b <- b*4096+r*64+c) + granule swizzle by (d&7)
__global__ void k_conv(const float* __restrict__ wtr, const float* __restrict__ wc,
                       u16* __restrict__ wcat, const float* __restrict__ w0,
                       u16* __restrict__ w0bf) {
  int i = blockIdx.x * 256 + threadIdx.x;
  if (i < 128 * D_DIM) {
    float v = (i < 64 * D_DIM) ? wtr[i] : wc[i - 64 * D_DIM];
    wcat[i] = f2bf_bits(v);
  }
  int j = i - 128 * D_DIM;
  if (j >= 0 && j < D_DIM * F_DIM) {
    int d = j >> 13, f = j & 8191;
    int r = f >> 7, rem = f & 127;
    int c = rem >> 1, b = rem & 1;
    float v = w0[(size_t)d * 8192 + b * 4096 + r * 64 + c];
    w0bf[(size_t)d * 8192 + (f ^ ((d & 7) << 3))] = f2bf_bits(v);
  }
}

// ---------------- small MFMA GEMM (64x64 tile, BK=32, sync staging) — trct only ----------------
template <int BM, int BN, int WR, int WC>
__global__ __launch_bounds__(256) void gemm_bt(const u16* __restrict__ A,
                                               const u16* __restrict__ B,
                                               float* __restrict__ C, int M, int N, int K) {
  constexpr int BK = 32;
  constexpr int MT = BM / (WR * 16);
  constexpr int NT = BN / (WC * 16);
  constexpr int AG = BM / 64;
  constexpr int BG = BN / 64;
  __shared__ u16 sA[BM * BK];
  __shared__ u16 sB[BN * BK];
  const int m0 = blockIdx.x * BM;
  const int n0 = blockIdx.y * BN;
  const int tid = threadIdx.x;
  const int wave = tid >> 6;
  const int lane = tid & 63;
  const int wr = wave / WC;
  const int wc = wave % WC;
  const int row_l = tid >> 2;
  const int c8 = (tid & 3) << 3;
  const int frow = lane & 15;
  const int fcol = (lane >> 4) << 3;

  f32x4 acc[MT][NT];
#pragma unroll
  for (int i = 0; i < MT; ++i)
#pragma unroll
    for (int j = 0; j < NT; ++j) acc[i][j] = (f32x4){0.f, 0.f, 0.f, 0.f};

  for (int k0 = 0; k0 < K; k0 += BK) {
#pragma unroll
    for (int j = 0; j < AG; ++j) {
      uint4 v = *(const uint4*)(A + (size_t)(m0 + j * 64 + row_l) * K + (k0 + c8));
      *(uint4*)(sA + (j * 64 + row_l) * BK + c8) = v;
    }
#pragma unroll
    for (int j = 0; j < BG; ++j) {
      uint4 v = *(const uint4*)(B + (size_t)(n0 + j * 64 + row_l) * K + (k0 + c8));
      *(uint4*)(sB + (j * 64 + row_l) * BK + c8) = v;
    }
    __syncthreads();
    short8 af[MT], bfr[NT];
#pragma unroll
    for (int i = 0; i < MT; ++i)
      af[i] = *(const short8*)(sA + (wr * MT * 16 + i * 16 + frow) * BK + fcol);
#pragma unroll
    for (int j = 0; j < NT; ++j)
      bfr[j] = *(const short8*)(sB + (wc * NT * 16 + j * 16 + frow) * BK + fcol);
#pragma unroll
    for (int i = 0; i < MT; ++i)
#pragma unroll
      for (int j = 0; j < NT; ++j)
        acc[i][j] = __builtin_amdgcn_mfma_f32_16x16x32_bf16(af[i], bfr[j], acc[i][j], 0, 0, 0);
    __syncthreads();
  }
#pragma unroll
  for (int i = 0; i < MT; ++i) {
    const int rbase = m0 + wr * MT * 16 + i * 16 + ((lane >> 4) << 2);
#pragma unroll
    for (int j = 0; j < NT; ++j) {
      const int col = n0 + wc * NT * 16 + j * 16 + (lane & 15);
#pragma unroll
      for (int rg = 0; rg < 4; ++rg) C[(size_t)(rbase + rg) * N + col] = acc[i][j][rg];
    }
  }
}

// ---------------- 128x128 MFMA GEMM, BK=64, XOR-swizzled operands, split-K ----------------
// A, B global layout: row-major with 16B granule g of each row stored at g ^ (row&7)
// (within aligned 8-granule groups). gl_lds16's linear copy preserves this in LDS;
// fragment reads address granule ((kk*4+quad) ^ (frow&7)) -> conflict-free LDS.
__global__ __launch_bounds__(256) void gemm128(const u16* __restrict__ A,
                                               const u16* __restrict__ B,
                                               float* __restrict__ Cp, size_t pstride, int N,
                                               int Ktot) {
  __shared__ u16 sA[128 * 64];
  __shared__ u16 sB[128 * 64];
  const int tid = threadIdx.x;
  const int wave = tid >> 6;
  const int lane = tid & 63;
  const int wr = wave >> 1;
  const int wc = wave & 1;
  const int m0 = blockIdx.x * 128;
  const int n0 = blockIdx.y * 128;
  const int ks = blockIdx.z;
  const int Kper = Ktot / gridDim.z;
  const int kb = ks * Kper;
  const int row_s = tid >> 3;     // 0..31 staging row within 32-row group
  const int g8 = (tid & 7) << 3;  // granule offset (elems)
  const int frow = lane & 15;
  const int quad = lane >> 4;
  const int sw = frow & 7;

  f32x4 acc[4][4];
#pragma unroll
  for (int i = 0; i < 4; ++i)
#pragma unroll
    for (int j = 0; j < 4; ++j) acc[i][j] = (f32x4){0.f, 0.f, 0.f, 0.f};

  for (int k0 = kb; k0 < kb + Kper; k0 += 64) {
#pragma unroll
    for (int j = 0; j < 4; ++j) {
      gl_lds16(A + (size_t)(m0 + j * 32 + row_s) * Ktot + (k0 + g8), sA + j * 2048 + wave * 512);
      gl_lds16(B + (size_t)(n0 + j * 32 + row_s) * Ktot + (k0 + g8), sB + j * 2048 + wave * 512);
    }
    asm volatile("s_waitcnt vmcnt(0)" ::: "memory");
    __syncthreads();
#pragma unroll
    for (int kk = 0; kk < 2; ++kk) {
      const int gA = (((kk << 2) | quad) ^ sw) << 3;  // swizzled elem offset in row
      short8 af[4], bfr[4];
#pragma unroll
      for (int i = 0; i < 4; ++i)
        af[i] = *(const short8*)(sA + (wr * 64 + i * 16 + frow) * 64 + gA);
#pragma unroll
      for (int j = 0; j < 4; ++j)
        bfr[j] = *(const short8*)(sB + (wc * 64 + j * 16 + frow) * 64 + gA);
#pragma unroll
      for (int i = 0; i < 4; ++i)
#pragma unroll
        for (int j = 0; j < 4; ++j)
          acc[i][j] = __builtin_amdgcn_mfma_f32_16x16x32_bf16(af[i], bfr[j], acc[i][j], 0, 0, 0);
    }
    __syncthreads();
  }
#pragma unroll
  for (int i = 0; i < 4; ++i) {
    const int rbase = m0 + wr * 64 + i * 16 + ((lane >> 4) << 2);
#pragma unroll
    for (int j = 0; j < 4; ++j) {
      const int col = n0 + wc * 64 + j * 16 + (lane & 15);
#pragma unroll
      for (int rg = 0; rg < 4; ++rg)
        Cp[(size_t)ks * pstride + (size_t)(rbase + rg) * N + col] = acc[i][j][rg];
    }
  }
}

// ---------------- p/q prep: pT=|tr| transposed, q=|ct|/(1e-8+Sp*Sq) ----------------
__global__ void prep_pq(const float* __restrict__ trct, float* __restrict__ pT,
                        float* __restrict__ q) {
  int t = blockIdx.x;
  int lane = threadIdx.x;  // 64
  float tr = trct[t * 128 + lane];
  float ct = trct[t * 128 + 64 + lane];
  float ap = fabsf(tr), aq = fabsf(ct);
  float Sp = wave_sum(ap);
  float Sq = wave_sum(aq);
  float denom = 1e-8f + Sp * Sq;
  pT[lane * T_LEN + t] = ap;  // transposed for shuffle-broadcast in scans
  q[t * 64 + lane] = aq / denom;
}

// ---------------- scan phase 1: per-chunk affine summary (A,B) ----------------
// A = any_start ? 0 : e^64. B: any start zeroes all earlier terms, so only steps
// i >= L (L = last start) survive: Horner from i=L.
__global__ void scan_phase1(const float* __restrict__ pT, const float* __restrict__ q,
                            const unsigned char* __restrict__ st8, const int* __restrict__ st32,
                            const int* __restrict__ modep, const float* __restrict__ a,
                            const float* __restrict__ b, float4* __restrict__ chunkbuf) {
  int chunk = blockIdx.x, r = blockIdx.y, c = threadIdx.x;
  int mode = modep[0];
  int t0 = chunk * CLEN;
  float na = -fabsf(a[r]);
  float rho = __expf(na);
  float bb = b[c];
  float er = rho * __cosf(bb), ei = rho * __sinf(bb);
  float pv = pT[r * T_LEN + t0 + c];             // lane c holds p for step c
  int sv = read_start(st8, st32, mode, t0 + c);  // lane c holds start for step c
  unsigned long long bal = __ballot(sv != 0);
  float Ar, Ai;
  if (bal) {
    Ar = 0.f; Ai = 0.f;
  } else {
    float mag = __expf(64.f * na);
    float ang = 64.f * bb;
    Ar = mag * __cosf(ang);
    Ai = mag * __sinf(ang);
  }
  int L = bal ? (63 - __builtin_clzll(bal)) : 0;  // wave-uniform
  float Br = 0.f, Bi = 0.f;
  const float* qrow = q + (size_t)t0 * 64 + c;
  for (int i = L; i < CLEN; ++i) {
    float pre = __shfl(pv, i) * qrow[i * 64];
    float nBr = er * Br - ei * Bi + pre;
    Bi = er * Bi + ei * Br;
    Br = nBr;
  }
  chunkbuf[((size_t)chunk * 64 + r) * 64 + c] = make_float4(Ar, Ai, Br, Bi);
}

// ---------------- scan phase 2: sequential chunk combine ----------------
__global__ void scan_phase2(const float4* __restrict__ chunkbuf, const float* __restrict__ state,
                            float2* __restrict__ s0buf) {
  int r = blockIdx.x, c = threadIdx.x;
  float Sr = state[r * 64 + c], Si = 0.f;
  for (int k = 0; k < NCHUNK; ++k) {
    s0buf[((size_t)k * 64 + r) * 64 + c] = make_float2(Sr, Si);
    float4 ab = chunkbuf[((size_t)k * 64 + r) * 64 + c];
    float nSr = ab.x * Sr - ab.y * Si + ab.z;
    Si = ab.x * Si + ab.y * Sr + ab.w;
    Sr = nSr;
  }
}

// ---------------- scan phase 3: replay + packed log-polar features (swizzled store) ----
// logical dword index L = r*64+c; stored at L ^ ((t&7)<<2) to match gemm128's layout.
__global__ void scan_phase3(const float* __restrict__ pT, const float* __restrict__ q,
                            const unsigned char* __restrict__ st8, const int* __restrict__ st32,
                            const int* __restrict__ modep, const float* __restrict__ a,
                            const float* __restrict__ b, const float2* __restrict__ s0buf,
                            u32* __restrict__ scaled, int c0) {
  int chunk = c0 + blockIdx.x, r = blockIdx.y, c = threadIdx.x;
  int mode = modep[0];
  int t0 = chunk * CLEN;
  float rho = __expf(-fabsf(a[r]));
  float bb = b[c];
  float er = rho * __cosf(bb), ei = rho * __sinf(bb);
  float pv = pT[r * T_LEN + t0 + c];
  int sv = read_start(st8, st32, mode, t0 + c);
  float2 s0 = s0buf[((size_t)chunk * 64 + r) * 64 + c];
  float Sr = s0.x, Si = s0.y;
  int tl0 = (chunk - c0) * CLEN;
  const float* qrow = q + (size_t)t0 * 64 + c;
  u32* srow = scaled + (size_t)tl0 * 4096;
  const int Ldw = r * 64 + c;
#pragma unroll 4
  for (int i = 0; i < CLEN; ++i) {
    float qt = qrow[i * 64];
    float pt = __shfl(pv, i);
    int st = __shfl(sv, i);
    float pre = pt * qt;
    float cer = st ? 0.f : er;
    float cei = st ? 0.f : ei;
    float nSr = cer * Sr - cei * Si + pre;
    Si = cer * Si + cei * Sr;
    Sr = nSr;
    // sc = log1p(m)/m via hw log2/rsq; rel err ~6e-4 << bf16 quantization
    float m2 = fmaf(Sr, Sr, Si * Si);
    float rsq = rsqrtf(fmaxf(m2, 1e-30f));
    float m = m2 * rsq;
    float sc = __log2f(1.0f + m) * 0.6931471805599453f * rsq;
    u32 pack = ((u32)f2bf_bits(sc * Sr) << 16) | (u32)f2bf_bits(sc * Si);
    srow[(size_t)i * 4096 + (Ldw ^ ((i & 7) << 2))] = pack;
  }
}

// ---------------- LayerNorm + LeakyReLU over summed split-K partials ----------------
// zbf written with gemm128's granule swizzle (by t&7); xbf_next unswizzled (BK=32 gemm).
__global__ void ln_act(const float* __restrict__ parts, int KS, size_t pstride,
                       const float* __restrict__ bias, const float* __restrict__ gam,
                       const float* __restrict__ bet, u16* __restrict__ zbf,
                       const float* __restrict__ xsrc, float* __restrict__ xdst,
                       u16* __restrict__ xbf_next, float* __restrict__ finout) {
  __shared__ float red[8];
  int t = blockIdx.x, tid = threadIdx.x;
  size_t o = (size_t)t * D_DIM + tid;
  float v0 = bias[tid];
  float v1 = bias[tid + 256];
  for (int ks = 0; ks < KS; ++ks) {
    v0 += parts[(size_t)ks * pstride + o];
    v1 += parts[(size_t)ks * pstride + o + 256];
  }
  float s = wave_sum(v0 + v1);
  if ((tid & 63) == 0) red[tid >> 6] = s;
  __syncthreads();
  float mean = (red[0] + red[1] + red[2] + red[3]) * (1.f / 512.f);
  float d0 = v0 - mean, d1 = v1 - mean;
  float s2 = wave_sum(d0 * d0 + d1 * d1);
  if ((tid & 63) == 0) red[4 + (tid >> 6)] = s2;
  __syncthreads();
  float var = (red[4] + red[5] + red[6] + red[7]) * (1.f / 512.f);
  float rstd = rsqrtf(var + 1e-5f);
  float z0 = d0 * rstd * gam[tid] + bet[tid];
  float z1 = d1 * rstd * gam[tid + 256] + bet[tid + 256];
  z0 = z0 > 0.f ? z0 : 0.01f * z0;
  z1 = z1 > 0.f ? z1 : 0.01f * z1;
  if (zbf) {
    int sw8 = (t & 7) << 3;
    size_t zb = (size_t)t * D_DIM;
    zbf[zb + (tid ^ sw8)] = f2bf_bits(z0);
    zbf[zb + 256 + (tid ^ sw8)] = f2bf_bits(z1);
  }
  if (xdst) {
    float x0 = xsrc[o] + z0, x1 = xsrc[o + 256] + z1;
    xdst[o] = x0; xdst[o + 256] = x1;
    if (xbf_next) { xbf_next[o] = f2bf_bits(x0); xbf_next[o + 256] = f2bf_bits(x1); }
  }
  if (finout) { finout[o] = z0; finout[o + 256] = z1; }
}

__global__ void err_signal(float* __restrict__ out, float code) {
  if (threadIdx.x == 0) out[0] = code;
}

// ---------------- host launch ----------------
extern "C" void kernel_launch(void* const* d_in, const int* in_sizes, int n_in, void* d_out,
                              int out_size, void* d_ws, size_t ws_size, hipStream_t stream) {
  const float* x_in = (const float*)d_in[0];
  const float* state = (const float*)d_in[1];
  const unsigned char* start8 = (const unsigned char*)d_in[2];
  const int* start32 = (const int*)d_in[2];
  const float* Wtr = (const float*)d_in[3];
  const float* Wc = (const float*)d_in[4];
  const float* a_in = (const float*)d_in[5];
  const float* b_in = (const float*)d_in[6];
  const float* W0 = (const float*)d_in[7];
  const float* b0 = (const float*)d_in[8];
  const float* g0 = (const float*)d_in[9];
  const float* beta0 = (const float*)d_in[10];
  const float* W1 = (const float*)d_in[11];
  const float* b1 = (const float*)d_in[12];
  const float* g1 = (const float*)d_in[13];
  const float* beta1 = (const float*)d_in[14];
  float* out = (float*)d_out;

  char* w = (char*)d_ws;
  auto alloc = [&](size_t bytes) {
    char* ptr = w;
    w += (bytes + 255) & ~(size_t)255;
    return ptr;
  };
  float* x_ws = (float*)alloc(4ull * T_LEN * D_DIM);            // 8 MB
  u16* xbf = (u16*)alloc(2ull * T_LEN * D_DIM);                 // 4 MB
  u16* wcat = (u16*)alloc(2ull * 128 * D_DIM);                  // 128 KB
  u16* w0bf = (u16*)alloc(2ull * D_DIM * F_DIM);                // 8 MB (per-layer)
  u16* w1bf = (u16*)alloc(2ull * 3 * D_DIM * D_DIM);            // 1.5 MB (all layers)
  float* trct = (float*)alloc(4ull * T_LEN * 128);              // 2 MB
  float* pTbuf = (float*)alloc(4ull * T_LEN * 64);              // 1 MB
  float* qbuf = (float*)alloc(4ull * T_LEN * 64);               // 1 MB
  float4* chunkbuf = (float4*)alloc(16ull * NCHUNK * 64 * 64);  // 4 MB
  float2* s0buf = (float2*)alloc(8ull * NCHUNK * 64 * 64);      // 2 MB
  u16* z0bf = (u16*)alloc(2ull * T_LEN * D_DIM);                // 4 MB
  int* modep = (int*)alloc(256);
  size_t base1 = (size_t)(w - (char*)d_ws);

  if (n_in != 15) {
    err_signal<<<1, 64, 0, stream>>>(out, 9e6f + 1000.f * n_in);
    return;
  }
  const size_t MB = 1ull << 20;
  int KS, nseg;
  if (ws_size >= base1 + 64 * MB + 64 * MB) { KS = 8; nseg = 1; }
  else if (ws_size >= base1 + 32 * MB + 64 * MB) { KS = 4; nseg = 1; }
  else if (ws_size >= base1 + 32 * MB + 32 * MB) { KS = 4; nseg = 2; }
  else if (ws_size >= base1 + 16 * MB + 32 * MB) { KS = 2; nseg = 2; }
  else if (ws_size >= base1 + 16 * MB + 16 * MB) { KS = 2; nseg = 4; }
  else if (ws_size >= base1 + 8 * MB + 16 * MB) { KS = 1; nseg = 4; }
  else {
    err_signal<<<1, 64, 0, stream>>>(out, 9e6f);
    return;
  }
  const int KSw1 = (KS >= 8) ? 4 : ((KS >= 2) ? 2 : 1);
  const int seg_rows = T_LEN / nseg;
  const int seg_chunks = NCHUNK / nseg;
  const size_t pstride = (size_t)T_LEN * D_DIM;
  float* ypart = (float*)alloc(4ull * KS * pstride);
  u16* scaled = (u16*)alloc(2ull * seg_rows * F_DIM);

  detect_start<<<1, 256, 0, stream>>>(start8, modep);
  f2bf<<<(T_LEN * D_DIM) / 256, 256, 0, stream>>>(x_in, xbf, T_LEN * D_DIM);
  k_w1conv<<<(3 * D_DIM * D_DIM) / 256, 256, 0, stream>>>(W1, w1bf, 3 * D_DIM * D_DIM);

  for (int l = 0; l < 3; ++l) {
    const float* Wtr_l = Wtr + (size_t)l * 64 * D_DIM;
    const float* Wc_l = Wc + (size_t)l * 64 * D_DIM;
    const float* a_l = a_in + l * 64;
    const float* b_l = b_in + l * 64;
    const float* W0_l = W0 + (size_t)l * D_DIM * F_DIM;
    const u16* w1bf_l = w1bf + (size_t)l * D_DIM * D_DIM;
    const float* state_l = state + (size_t)l * 64 * 64;
    const float* xsrc = (l == 0) ? x_in : x_ws;

    k_conv<<<(128 * D_DIM + D_DIM * F_DIM) / 256, 256, 0, stream>>>(Wtr_l, Wc_l, wcat, W0_l,
                                                                    w0bf);
    // trct (4096 x 128) = xbf @ wcat^T
    gemm_bt<64, 64, 2, 2><<<dim3(T_LEN / 64, 2), 256, 0, stream>>>(xbf, wcat, trct, T_LEN, 128,
                                                                   D_DIM);
    prep_pq<<<T_LEN, 64, 0, stream>>>(trct, pTbuf, qbuf);
    scan_phase1<<<dim3(NCHUNK, 64), 64, 0, stream>>>(pTbuf, qbuf, start8, start32, modep, a_l,
                                                     b_l, chunkbuf);
    scan_phase2<<<64, 64, 0, stream>>>(chunkbuf, state_l, s0buf);

    for (int h = 0; h < nseg; ++h) {
      scan_phase3<<<dim3(seg_chunks, 64), 64, 0, stream>>>(pTbuf, qbuf, start8, start32, modep,
                                                           a_l, b_l, s0buf, (u32*)scaled,
                                                           h * seg_chunks);
      gemm128<<<dim3(seg_rows / 128, D_DIM / 128, KS), 256, 0, stream>>>(
          scaled, w0bf, ypart + (size_t)h * seg_rows * D_DIM, pstride, D_DIM, F_DIM);
    }
    ln_act<<<T_LEN, 256, 0, stream>>>(ypart, KS, pstride, b0 + l * D_DIM, g0 + l * D_DIM,
                                      beta0 + l * D_DIM, z0bf, nullptr, nullptr, nullptr,
                                      nullptr);
    gemm128<<<dim3(T_LEN / 128, D_DIM / 128, KSw1), 256, 0, stream>>>(z0bf, w1bf_l, ypart,
                                                                      pstride, D_DIM, D_DIM);
    ln_act<<<T_LEN, 256, 0, stream>>>(ypart, KSw1, pstride, b1 + l * D_DIM, g1 + l * D_DIM,
                                      beta1 + l * D_DIM, nullptr, (l < 2) ? xsrc : nullptr,
                                      (l < 2) ? x_ws : nullptr, (l < 2) ? xbf : nullptr,
                                      (l == 2) ? out : nullptr);
  }
}

// Round 11
// 518.708 us; speedup vs baseline: 1.0744x; 1.0744x over previous
//
#include <hip/hip_runtime.h>
#include <hip/hip_bf16.h>
#include <math.h>

#define T_LEN 4096
#define D_DIM 512
#define F_DIM 8192
#define NCHUNK 64
#define CLEN 64

typedef short short8 __attribute__((ext_vector_type(8)));
typedef float f32x4 __attribute__((ext_vector_type(4)));
typedef unsigned short u16;
typedef unsigned int u32;

// ---------------- helpers ----------------
__device__ inline float wave_sum(float v) {
#pragma unroll
  for (int o = 32; o; o >>= 1) v += __shfl_xor(v, o);
  return v;
}

__device__ inline u16 f2bf_bits(float v) {
  __hip_bfloat16 h = __float2bfloat16(v);
  return *(u16*)&h;
}

__device__ inline float bf2f(u16 u) {
  u32 x = ((u32)u) << 16;
  return *(float*)&x;
}

__device__ inline void gl_lds16(const void* g, void* l) {
  __builtin_amdgcn_global_load_lds((const __attribute__((address_space(1))) void*)g,
                                   (__attribute__((address_space(3))) void*)l, 16, 0, 0);
}

// start[] may arrive as 1-byte bools or int32 {0,1}.
__global__ void detect_start(const unsigned char* __restrict__ s8, int* __restrict__ mode) {
  __shared__ int found;
  if (threadIdx.x == 0) found = 0;
  __syncthreads();
  for (int i = threadIdx.x; i < 4096; i += 256)
    if ((i & 3) && s8[i]) found = 1;  // benign race, same value
  __syncthreads();
  if (threadIdx.x == 0) mode[0] = found;  // 1 = byte layout, 0 = int32 layout
}

__device__ inline int read_start(const unsigned char* s8, const int* s32, int mode, int t) {
  return mode ? (int)s8[t] : s32[t];
}

// ---------------- fp32 -> bf16(bits) convert (plain) ----------------
__global__ void f2bf(const float* __restrict__ s, u16* __restrict__ d, int n) {
  int i = blockIdx.x * 256 + threadIdx.x;
  if (i < n) d[i] = f2bf_bits(s[i]);
}

// fused per-layer weight conversion:
//   wcat = concat [Wtr_l; Wc_l] (128 x 512), unswizzled (BK=32 gemm)
//   w0bf: K-permute (f = r*128+2c+b <- b*4096+r*64+c) + granule swizzle by (d&7)
__global__ void k_conv(const float* __restrict__ wtr, const float* __restrict__ wc,
                       u16* __restrict__ wcat, const float* __restrict__ w0,
                       u16* __restrict__ w0bf) {
  int i = blockIdx.x * 256 + threadIdx.x;
  if (i < 128 * D_DIM) {
    float v = (i < 64 * D_DIM) ? wtr[i] : wc[i - 64 * D_DIM];
    wcat[i] = f2bf_bits(v);
  }
  int j = i - 128 * D_DIM;
  if (j >= 0 && j < D_DIM * F_DIM) {
    int d = j >> 13, f = j & 8191;
    int r = f >> 7, rem = f & 127;
    int c = rem >> 1, b = rem & 1;
    float v = w0[(size_t)d * 8192 + b * 4096 + r * 64 + c];
    w0bf[(size_t)d * 8192 + (f ^ ((d & 7) << 3))] = f2bf_bits(v);
  }
}

// ---------------- small MFMA GEMM (64x64 tile, BK=32, sync staging) — trct & W1 ----------------
template <int BM, int BN, int WR, int WC>
__global__ __launch_bounds__(256) void gemm_bt(const u16* __restrict__ A,
                                               const u16* __restrict__ B,
                                               float* __restrict__ C, int M, int N, int K) {
  constexpr int BK = 32;
  constexpr int MT = BM / (WR * 16);
  constexpr int NT = BN / (WC * 16);
  constexpr int AG = BM / 64;
  constexpr int BG = BN / 64;
  __shared__ u16 sA[BM * BK];
  __shared__ u16 sB[BN * BK];
  const int m0 = blockIdx.x * BM;
  const int n0 = blockIdx.y * BN;
  const int tid = threadIdx.x;
  const int wave = tid >> 6;
  const int lane = tid & 63;
  const int wr = wave / WC;
  const int wc = wave % WC;
  const int row_l = tid >> 2;
  const int c8 = (tid & 3) << 3;
  const int frow = lane & 15;
  const int fcol = (lane >> 4) << 3;

  f32x4 acc[MT][NT];
#pragma unroll
  for (int i = 0; i < MT; ++i)
#pragma unroll
    for (int j = 0; j < NT; ++j) acc[i][j] = (f32x4){0.f, 0.f, 0.f, 0.f};

  for (int k0 = 0; k0 < K; k0 += BK) {
#pragma unroll
    for (int j = 0; j < AG; ++j) {
      uint4 v = *(const uint4*)(A + (size_t)(m0 + j * 64 + row_l) * K + (k0 + c8));
      *(uint4*)(sA + (j * 64 + row_l) * BK + c8) = v;
    }
#pragma unroll
    for (int j = 0; j < BG; ++j) {
      uint4 v = *(const uint4*)(B + (size_t)(n0 + j * 64 + row_l) * K + (k0 + c8));
      *(uint4*)(sB + (j * 64 + row_l) * BK + c8) = v;
    }
    __syncthreads();
    short8 af[MT], bfr[NT];
#pragma unroll
    for (int i = 0; i < MT; ++i)
      af[i] = *(const short8*)(sA + (wr * MT * 16 + i * 16 + frow) * BK + fcol);
#pragma unroll
    for (int j = 0; j < NT; ++j)
      bfr[j] = *(const short8*)(sB + (wc * NT * 16 + j * 16 + frow) * BK + fcol);
#pragma unroll
    for (int i = 0; i < MT; ++i)
#pragma unroll
      for (int j = 0; j < NT; ++j)
        acc[i][j] = __builtin_amdgcn_mfma_f32_16x16x32_bf16(af[i], bfr[j], acc[i][j], 0, 0, 0);
    __syncthreads();
  }
#pragma unroll
  for (int i = 0; i < MT; ++i) {
    const int rbase = m0 + wr * MT * 16 + i * 16 + ((lane >> 4) << 2);
#pragma unroll
    for (int j = 0; j < NT; ++j) {
      const int col = n0 + wc * NT * 16 + j * 16 + (lane & 15);
#pragma unroll
      for (int rg = 0; rg < 4; ++rg) C[(size_t)(rbase + rg) * N + col] = acc[i][j][rg];
    }
  }
}

// ---------------- 128x128 MFMA GEMM, BK=64, XOR-swizzled operands, split-K, bf16 partials ----
// A, B global layout: row-major with 16B granule g of each row stored at g ^ (row&7).
__global__ __launch_bounds__(256) void gemm128(const u16* __restrict__ A,
                                               const u16* __restrict__ B,
                                               u16* __restrict__ Cp, size_t pstride, int N,
                                               int Ktot) {
  __shared__ u16 sA[128 * 64];
  __shared__ u16 sB[128 * 64];
  const int tid = threadIdx.x;
  const int wave = tid >> 6;
  const int lane = tid & 63;
  const int wr = wave >> 1;
  const int wc = wave & 1;
  const int m0 = blockIdx.x * 128;
  const int n0 = blockIdx.y * 128;
  const int ks = blockIdx.z;
  const int Kper = Ktot / gridDim.z;
  const int kb = ks * Kper;
  const int row_s = tid >> 3;     // 0..31 staging row within 32-row group
  const int g8 = (tid & 7) << 3;  // granule offset (elems)
  const int frow = lane & 15;
  const int quad = lane >> 4;
  const int sw = frow & 7;

  f32x4 acc[4][4];
#pragma unroll
  for (int i = 0; i < 4; ++i)
#pragma unroll
    for (int j = 0; j < 4; ++j) acc[i][j] = (f32x4){0.f, 0.f, 0.f, 0.f};

  for (int k0 = kb; k0 < kb + Kper; k0 += 64) {
#pragma unroll
    for (int j = 0; j < 4; ++j) {
      gl_lds16(A + (size_t)(m0 + j * 32 + row_s) * Ktot + (k0 + g8), sA + j * 2048 + wave * 512);
      gl_lds16(B + (size_t)(n0 + j * 32 + row_s) * Ktot + (k0 + g8), sB + j * 2048 + wave * 512);
    }
    asm volatile("s_waitcnt vmcnt(0)" ::: "memory");
    __syncthreads();
#pragma unroll
    for (int kk = 0; kk < 2; ++kk) {
      const int gA = (((kk << 2) | quad) ^ sw) << 3;  // swizzled elem offset in row
      short8 af[4], bfr[4];
#pragma unroll
      for (int i = 0; i < 4; ++i)
        af[i] = *(const short8*)(sA + (wr * 64 + i * 16 + frow) * 64 + gA);
#pragma unroll
      for (int j = 0; j < 4; ++j)
        bfr[j] = *(const short8*)(sB + (wc * 64 + j * 16 + frow) * 64 + gA);
#pragma unroll
      for (int i = 0; i < 4; ++i)
#pragma unroll
        for (int j = 0; j < 4; ++j)
          acc[i][j] = __builtin_amdgcn_mfma_f32_16x16x32_bf16(af[i], bfr[j], acc[i][j], 0, 0, 0);
    }
    __syncthreads();
  }
#pragma unroll
  for (int i = 0; i < 4; ++i) {
    const int rbase = m0 + wr * 64 + i * 16 + ((lane >> 4) << 2);
#pragma unroll
    for (int j = 0; j < 4; ++j) {
      const int col = n0 + wc * 64 + j * 16 + (lane & 15);
#pragma unroll
      for (int rg = 0; rg < 4; ++rg)
        Cp[(size_t)ks * pstride + (size_t)(rbase + rg) * N + col] = f2bf_bits(acc[i][j][rg]);
    }
  }
}

// ---------------- p/q prep: pT=|tr| transposed, q=|ct|/(1e-8+Sp*Sq) ----------------
__global__ void prep_pq(const float* __restrict__ trct, float* __restrict__ pT,
                        float* __restrict__ q) {
  int t = blockIdx.x;
  int lane = threadIdx.x;  // 64
  float tr = trct[t * 128 + lane];
  float ct = trct[t * 128 + 64 + lane];
  float ap = fabsf(tr), aq = fabsf(ct);
  float Sp = wave_sum(ap);
  float Sq = wave_sum(aq);
  float denom = 1e-8f + Sp * Sq;
  pT[lane * T_LEN + t] = ap;  // transposed for shuffle-broadcast in scans
  q[t * 64 + lane] = aq / denom;
}

// ---------------- scan phase 1: per-chunk affine summary (A,B) ----------------
__global__ void scan_phase1(const float* __restrict__ pT, const float* __restrict__ q,
                            const unsigned char* __restrict__ st8, const int* __restrict__ st32,
                            const int* __restrict__ modep, const float* __restrict__ a,
                            const float* __restrict__ b, float4* __restrict__ chunkbuf) {
  int chunk = blockIdx.x, r = blockIdx.y, c = threadIdx.x;
  int mode = modep[0];
  int t0 = chunk * CLEN;
  float na = -fabsf(a[r]);
  float rho = __expf(na);
  float bb = b[c];
  float er = rho * __cosf(bb), ei = rho * __sinf(bb);
  float pv = pT[r * T_LEN + t0 + c];             // lane c holds p for step c
  int sv = read_start(st8, st32, mode, t0 + c);  // lane c holds start for step c
  unsigned long long bal = __ballot(sv != 0);
  float Ar, Ai;
  if (bal) {
    Ar = 0.f; Ai = 0.f;
  } else {
    float mag = __expf(64.f * na);
    float ang = 64.f * bb;
    Ar = mag * __cosf(ang);
    Ai = mag * __sinf(ang);
  }
  int L = bal ? (63 - __builtin_clzll(bal)) : 0;  // wave-uniform
  float Br = 0.f, Bi = 0.f;
  const float* qrow = q + (size_t)t0 * 64 + c;
  for (int i = L; i < CLEN; ++i) {
    float pre = __shfl(pv, i) * qrow[i * 64];
    float nBr = er * Br - ei * Bi + pre;
    Bi = er * Bi + ei * Br;
    Br = nBr;
  }
  chunkbuf[((size_t)chunk * 64 + r) * 64 + c] = make_float4(Ar, Ai, Br, Bi);
}

// ---------------- scan phase 2: sequential chunk combine ----------------
__global__ void scan_phase2(const float4* __restrict__ chunkbuf, const float* __restrict__ state,
                            float2* __restrict__ s0buf) {
  int r = blockIdx.x, c = threadIdx.x;
  float Sr = state[r * 64 + c], Si = 0.f;
  for (int k = 0; k < NCHUNK; ++k) {
    s0buf[((size_t)k * 64 + r) * 64 + c] = make_float2(Sr, Si);
    float4 ab = chunkbuf[((size_t)k * 64 + r) * 64 + c];
    float nSr = ab.x * Sr - ab.y * Si + ab.z;
    Si = ab.x * Si + ab.y * Sr + ab.w;
    Sr = nSr;
  }
}

// ---------------- scan phase 3: replay + packed log-polar features (swizzled store) ----
__global__ void scan_phase3(const float* __restrict__ pT, const float* __restrict__ q,
                            const unsigned char* __restrict__ st8, const int* __restrict__ st32,
                            const int* __restrict__ modep, const float* __restrict__ a,
                            const float* __restrict__ b, const float2* __restrict__ s0buf,
                            u32* __restrict__ scaled, int c0) {
  int chunk = c0 + blockIdx.x, r = blockIdx.y, c = threadIdx.x;
  int mode = modep[0];
  int t0 = chunk * CLEN;
  float rho = __expf(-fabsf(a[r]));
  float bb = b[c];
  float er = rho * __cosf(bb), ei = rho * __sinf(bb);
  float pv = pT[r * T_LEN + t0 + c];
  int sv = read_start(st8, st32, mode, t0 + c);
  float2 s0 = s0buf[((size_t)chunk * 64 + r) * 64 + c];
  float Sr = s0.x, Si = s0.y;
  int tl0 = (chunk - c0) * CLEN;
  const float* qrow = q + (size_t)t0 * 64 + c;
  u32* srow = scaled + (size_t)tl0 * 4096;
  const int Ldw = r * 64 + c;
#pragma unroll 4
  for (int i = 0; i < CLEN; ++i) {
    float qt = qrow[i * 64];
    float pt = __shfl(pv, i);
    int st = __shfl(sv, i);
    float pre = pt * qt;
    float cer = st ? 0.f : er;
    float cei = st ? 0.f : ei;
    float nSr = cer * Sr - cei * Si + pre;
    Si = cer * Si + cei * Sr;
    Sr = nSr;
    float m2 = fmaf(Sr, Sr, Si * Si);
    float rsq = rsqrtf(fmaxf(m2, 1e-30f));
    float m = m2 * rsq;
    float sc = __log2f(1.0f + m) * 0.6931471805599453f * rsq;
    u32 pack = ((u32)f2bf_bits(sc * Sr) << 16) | (u32)f2bf_bits(sc * Si);
    srow[(size_t)i * 4096 + (Ldw ^ ((i & 7) << 2))] = pack;
  }
}

// ---------------- LN + LeakyReLU over bf16 split-K partials -> z0bf (unswizzled) ----------------
__global__ void ln_act16(const u16* __restrict__ parts, int KS, size_t pstride,
                         const float* __restrict__ bias, const float* __restrict__ gam,
                         const float* __restrict__ bet, u16* __restrict__ zbf) {
  __shared__ float red[8];
  int t = blockIdx.x, tid = threadIdx.x;
  size_t o = (size_t)t * D_DIM + tid;
  float v0 = bias[tid];
  float v1 = bias[tid + 256];
  for (int ks = 0; ks < KS; ++ks) {
    v0 += bf2f(parts[(size_t)ks * pstride + o]);
    v1 += bf2f(parts[(size_t)ks * pstride + o + 256]);
  }
  float s = wave_sum(v0 + v1);
  if ((tid & 63) == 0) red[tid >> 6] = s;
  __syncthreads();
  float mean = (red[0] + red[1] + red[2] + red[3]) * (1.f / 512.f);
  float d0 = v0 - mean, d1 = v1 - mean;
  float s2 = wave_sum(d0 * d0 + d1 * d1);
  if ((tid & 63) == 0) red[4 + (tid >> 6)] = s2;
  __syncthreads();
  float var = (red[4] + red[5] + red[6] + red[7]) * (1.f / 512.f);
  float rstd = rsqrtf(var + 1e-5f);
  float z0 = d0 * rstd * gam[tid] + bet[tid];
  float z1 = d1 * rstd * gam[tid + 256] + bet[tid + 256];
  z0 = z0 > 0.f ? z0 : 0.01f * z0;
  z1 = z1 > 0.f ? z1 : 0.01f * z1;
  zbf[o] = f2bf_bits(z0);
  zbf[o + 256] = f2bf_bits(z1);
}

// ---------------- LN + LeakyReLU over fp32 y (W1 epilogue) ----------------
__global__ void ln_act32(const float* __restrict__ y, const float* __restrict__ bias,
                         const float* __restrict__ gam, const float* __restrict__ bet,
                         const float* __restrict__ xsrc, float* __restrict__ xdst,
                         u16* __restrict__ xbf_next, float* __restrict__ finout) {
  __shared__ float red[8];
  int t = blockIdx.x, tid = threadIdx.x;
  size_t o = (size_t)t * D_DIM + tid;
  float v0 = y[o] + bias[tid];
  float v1 = y[o + 256] + bias[tid + 256];
  float s = wave_sum(v0 + v1);
  if ((tid & 63) == 0) red[tid >> 6] = s;
  __syncthreads();
  float mean = (red[0] + red[1] + red[2] + red[3]) * (1.f / 512.f);
  float d0 = v0 - mean, d1 = v1 - mean;
  float s2 = wave_sum(d0 * d0 + d1 * d1);
  if ((tid & 63) == 0) red[4 + (tid >> 6)] = s2;
  __syncthreads();
  float var = (red[4] + red[5] + red[6] + red[7]) * (1.f / 512.f);
  float rstd = rsqrtf(var + 1e-5f);
  float z0 = d0 * rstd * gam[tid] + bet[tid];
  float z1 = d1 * rstd * gam[tid + 256] + bet[tid + 256];
  z0 = z0 > 0.f ? z0 : 0.01f * z0;
  z1 = z1 > 0.f ? z1 : 0.01f * z1;
  if (xdst) {
    float x0 = xsrc[o] + z0, x1 = xsrc[o + 256] + z1;
    xdst[o] = x0;
    xdst[o + 256] = x1;
    xbf_next[o] = f2bf_bits(x0);
    xbf_next[o + 256] = f2bf_bits(x1);
  }
  if (finout) {
    finout[o] = z0;
    finout[o + 256] = z1;
  }
}

__global__ void err_signal(float* __restrict__ out, float code) {
  if (threadIdx.x == 0) out[0] = code;
}

// ---------------- host launch ----------------
extern "C" void kernel_launch(void* const* d_in, const int* in_sizes, int n_in, void* d_out,
                              int out_size, void* d_ws, size_t ws_size, hipStream_t stream) {
  const float* x_in = (const float*)d_in[0];
  const float* state = (const float*)d_in[1];
  const unsigned char* start8 = (const unsigned char*)d_in[2];
  const int* start32 = (const int*)d_in[2];
  const float* Wtr = (const float*)d_in[3];
  const float* Wc = (const float*)d_in[4];
  const float* a_in = (const float*)d_in[5];
  const float* b_in = (const float*)d_in[6];
  const float* W0 = (const float*)d_in[7];
  const float* b0 = (const float*)d_in[8];
  const float* g0 = (const float*)d_in[9];
  const float* beta0 = (const float*)d_in[10];
  const float* W1 = (const float*)d_in[11];
  const float* b1 = (const float*)d_in[12];
  const float* g1 = (const float*)d_in[13];
  const float* beta1 = (const float*)d_in[14];
  float* out = (float*)d_out;

  char* w = (char*)d_ws;
  auto alloc = [&](size_t bytes) {
    char* ptr = w;
    w += (bytes + 255) & ~(size_t)255;
    return ptr;
  };
  float* x_ws = (float*)alloc(4ull * T_LEN * D_DIM);            // 8 MB
  u16* xbf = (u16*)alloc(2ull * T_LEN * D_DIM);                 // 4 MB
  u16* wcat = (u16*)alloc(2ull * 128 * D_DIM);                  // 128 KB
  u16* w0bf = (u16*)alloc(2ull * D_DIM * F_DIM);                // 8 MB (per-layer)
  u16* w1bf = (u16*)alloc(2ull * 3 * D_DIM * D_DIM);            // 1.5 MB (all layers)
  float* trct = (float*)alloc(4ull * T_LEN * 128);              // 2 MB
  float* pTbuf = (float*)alloc(4ull * T_LEN * 64);              // 1 MB
  float* qbuf = (float*)alloc(4ull * T_LEN * 64);               // 1 MB
  float4* chunkbuf = (float4*)alloc(16ull * NCHUNK * 64 * 64);  // 4 MB
  float2* s0buf = (float2*)alloc(8ull * NCHUNK * 64 * 64);      // 2 MB
  u16* z0bf = (u16*)alloc(2ull * T_LEN * D_DIM);                // 4 MB
  float* ybuf = (float*)alloc(4ull * T_LEN * D_DIM);            // 8 MB (W1 out)
  int* modep = (int*)alloc(256);
  size_t base1 = (size_t)(w - (char*)d_ws);

  if (n_in != 15) {
    err_signal<<<1, 64, 0, stream>>>(out, 9e6f + 1000.f * n_in);
    return;
  }
  const size_t MB = 1ull << 20;
  const size_t pstride = (size_t)T_LEN * D_DIM;  // elements per partial slab
  int KS, nseg;
  if (ws_size >= base1 + 16 * MB + 64 * MB) { KS = 4; nseg = 1; }
  else if (ws_size >= base1 + 16 * MB + 32 * MB) { KS = 4; nseg = 2; }
  else if (ws_size >= base1 + 8 * MB + 32 * MB) { KS = 2; nseg = 2; }
  else if (ws_size >= base1 + 8 * MB + 16 * MB) { KS = 2; nseg = 4; }
  else if (ws_size >= base1 + 4 * MB + 16 * MB) { KS = 1; nseg = 4; }
  else {
    err_signal<<<1, 64, 0, stream>>>(out, 9e6f);
    return;
  }
  const int seg_rows = T_LEN / nseg;
  const int seg_chunks = NCHUNK / nseg;
  u16* ypart = (u16*)alloc(2ull * KS * pstride);
  u16* scaled = (u16*)alloc(2ull * seg_rows * F_DIM);

  detect_start<<<1, 256, 0, stream>>>(start8, modep);
  f2bf<<<(T_LEN * D_DIM) / 256, 256, 0, stream>>>(x_in, xbf, T_LEN * D_DIM);
  f2bf<<<(3 * D_DIM * D_DIM) / 256, 256, 0, stream>>>(W1, w1bf, 3 * D_DIM * D_DIM);

  for (int l = 0; l < 3; ++l) {
    const float* Wtr_l = Wtr + (size_t)l * 64 * D_DIM;
    const float* Wc_l = Wc + (size_t)l * 64 * D_DIM;
    const float* a_l = a_in + l * 64;
    const float* b_l = b_in + l * 64;
    const float* W0_l = W0 + (size_t)l * D_DIM * F_DIM;
    const u16* w1bf_l = w1bf + (size_t)l * D_DIM * D_DIM;
    const float* state_l = state + (size_t)l * 64 * 64;
    const float* xsrc = (l == 0) ? x_in : x_ws;

    k_conv<<<(128 * D_DIM + D_DIM * F_DIM) / 256, 256, 0, stream>>>(Wtr_l, Wc_l, wcat, W0_l,
                                                                    w0bf);
    // trct (4096 x 128) = xbf @ wcat^T
    gemm_bt<64, 64, 2, 2><<<dim3(T_LEN / 64, 2), 256, 0, stream>>>(xbf, wcat, trct, T_LEN, 128,
                                                                   D_DIM);
    prep_pq<<<T_LEN, 64, 0, stream>>>(trct, pTbuf, qbuf);
    scan_phase1<<<dim3(NCHUNK, 64), 64, 0, stream>>>(pTbuf, qbuf, start8, start32, modep, a_l,
                                                     b_l, chunkbuf);
    scan_phase2<<<64, 64, 0, stream>>>(chunkbuf, state_l, s0buf);

    for (int h = 0; h < nseg; ++h) {
      scan_phase3<<<dim3(seg_chunks, 64), 64, 0, stream>>>(pTbuf, qbuf, start8, start32, modep,
                                                           a_l, b_l, s0buf, (u32*)scaled,
                                                           h * seg_chunks);
      gemm128<<<dim3(seg_rows / 128, D_DIM / 128, KS), 256, 0, stream>>>(
          scaled, w0bf, ypart + (size_t)h * seg_rows * D_DIM, pstride, D_DIM, F_DIM);
    }
    ln_act16<<<T_LEN, 256, 0, stream>>>(ypart, KS, pstride, b0 + l * D_DIM, g0 + l * D_DIM,
                                        beta0 + l * D_DIM, z0bf);
    // y2 = z0 (4096x512) @ W1 (512x512)^T — no split-K, grid 64x8 = 512 blocks
    gemm_bt<64, 64, 2, 2><<<dim3(T_LEN / 64, D_DIM / 64), 256, 0, stream>>>(z0bf, w1bf_l, ybuf,
                                                                            T_LEN, D_DIM, D_DIM);
    ln_act32<<<T_LEN, 256, 0, stream>>>(ybuf, b1 + l * D_DIM, g1 + l * D_DIM, beta1 + l * D_DIM,
                                        (l < 2) ? xsrc : nullptr, (l < 2) ? x_ws : nullptr,
                                        (l < 2) ? xbf : nullptr, (l == 2) ? out : nullptr);
  }
}